// Round 7
// baseline (442.069 us; speedup 1.0000x reference)
//
#include <hip/hip_runtime.h>
#include <hip/hip_cooperative_groups.h>

namespace cg = cooperative_groups;

struct Params {
  const float *X, *E, *nbr;
  const float *embW, *embB, *boutW, *boutB;
  const float *qpW, *qpB, *kpW, *kpB, *qoW, *qoB, *koW, *koB;
  const float *bpW, *bpB, *bowW, *bowB;
  const float *qlnG, *qlnB, *klnG, *klnB;
  float *out;
  float *q, *k, *pq, *pk, *pkT, *pred;       // pkT: double-buffered [2][512][256]
  float *zeroBias, *zeroDiff, *genBias, *genDiff;  // diffs double-buffered [2][4]
  int *map;
  float *specialDiff, *specialBias;
};

__device__ __forceinline__ float mishf(float x) {
  float sp = (x > 20.f) ? x : log1pf(expf(x));
  return x * tanhf(sp);
}

// One bias row through one layer (1024 threads, float4-vectorized):
//   b = row@Wp + Bp ; drow_h = ||b_h|| ; row' = mish(b@Wo + Bo)
__device__ void bias_row_pipe(float* __restrict__ row, float* __restrict__ drow,
                              const float* __restrict__ Wp, const float* __restrict__ Bp,
                              const float* __restrict__ Wo, const float* __restrict__ Bo,
                              float* smF, float* smG, float4* smV, int t) {
  const int lane = t & 63, wave = t >> 6;
  if (t < 128) smF[t] = row[t];
  __syncthreads();
  {                                      // GEMM1: 512 outs = 128 f4, 8 k-chunks x16
    const int og = t & 127, kc = t >> 7;
    const float4* Wp4 = (const float4*)Wp;
    const float* rc = smF + kc * 16;
    float4 a = {0.f, 0.f, 0.f, 0.f};
    #pragma unroll
    for (int cc = 0; cc < 16; ++cc) {
      float bv = rc[cc];
      float4 w = Wp4[(kc * 16 + cc) * 128 + og];
      a.x = fmaf(bv, w.x, a.x); a.y = fmaf(bv, w.y, a.y);
      a.z = fmaf(bv, w.z, a.z); a.w = fmaf(bv, w.w, a.w);
    }
    smV[t] = a;
  }
  __syncthreads();
  if (t < 128) {
    float4 a = smV[t];
    #pragma unroll
    for (int kc = 1; kc < 8; ++kc) {
      float4 v = smV[kc * 128 + t];
      a.x += v.x; a.y += v.y; a.z += v.z; a.w += v.w;
    }
    float4 bb = ((const float4*)Bp)[t];
    a.x += bb.x; a.y += bb.y; a.z += bb.z; a.w += bb.w;
    ((float4*)smG)[t] = a;                // b[512] in smG
  }
  __syncthreads();
  if (wave < 4) {                         // per-head norm
    float e1 = smG[wave * 128 + lane], e2 = smG[wave * 128 + 64 + lane];
    float s = e1 * e1 + e2 * e2;
    #pragma unroll
    for (int sh = 32; sh; sh >>= 1) s += __shfl_xor(s, sh);
    if (lane == 0) drow[wave] = sqrtf(s);
  }
  {                                      // GEMM2: 128 outs = 32 f4, 32 k-chunks x16
    const int og = t & 31, kc = t >> 5;
    const float4* Wo4 = (const float4*)Wo;
    const float* bc = smG + kc * 16;
    float4 a = {0.f, 0.f, 0.f, 0.f};
    #pragma unroll
    for (int oo = 0; oo < 16; ++oo) {
      float bv = bc[oo];
      float4 w = Wo4[(kc * 16 + oo) * 32 + og];
      a.x = fmaf(bv, w.x, a.x); a.y = fmaf(bv, w.y, a.y);
      a.z = fmaf(bv, w.z, a.z); a.w = fmaf(bv, w.w, a.w);
    }
    smV[t] = a;
  }
  __syncthreads();
  if (t < 32) {
    float4 a = smV[t];
    #pragma unroll
    for (int kc = 1; kc < 32; ++kc) {
      float4 v = smV[kc * 32 + t];
      a.x += v.x; a.y += v.y; a.z += v.z; a.w += v.w;
    }
    float4 bo = ((const float4*)Bo)[t];
    float4 r;
    r.x = mishf(a.x + bo.x); r.y = mishf(a.y + bo.y);
    r.z = mishf(a.z + bo.z); r.w = mishf(a.w + bo.w);
    ((float4*)row)[t] = r;
  }
  __syncthreads();
}

// projection of q,k (layer l) from xs in smH[0..127]; writes pq/pk + pkT[l&1]
__device__ void b_proj(const Params& P, int n, int t, int l, float* smH, float4* smV) {
  const int g = t >> 9, kc = (t >> 7) & 3, ug = t & 127;
  const float4* Wp4 = (const float4*)((g ? P.kpW : P.qpW) + (size_t)l * 32768);
  const float* xs = smH + g * 64 + kc * 16;
  float4 a = {0.f, 0.f, 0.f, 0.f};
  #pragma unroll
  for (int dd = 0; dd < 16; ++dd) {
    float x = xs[dd];
    float4 w = Wp4[(kc * 16 + dd) * 128 + ug];
    a.x = fmaf(x, w.x, a.x); a.y = fmaf(x, w.y, a.y);
    a.z = fmaf(x, w.z, a.z); a.w = fmaf(x, w.w, a.w);
  }
  smV[t] = a;
  __syncthreads();
  if (t < 256) {
    const int g2 = t >> 7, ug2 = t & 127;
    float4 r = smV[g2 * 512 + ug2];
    #pragma unroll
    for (int kc2 = 1; kc2 < 4; ++kc2) {
      float4 v = smV[g2 * 512 + kc2 * 128 + ug2];
      r.x += v.x; r.y += v.y; r.z += v.z; r.w += v.w;
    }
    float4 bb = ((const float4*)((g2 ? P.kpB : P.qpB) + l * 512))[ug2];
    r.x += bb.x; r.y += bb.y; r.z += bb.z; r.w += bb.w;
    if (g2) {
      ((float4*)(P.pk + n * 512))[ug2] = r;
      float* pkTl = P.pkT + (size_t)(l & 1) * 131072;
      const int u = ug2 * 4;
      pkTl[u * 256 + n] = r.x;       pkTl[(u + 1) * 256 + n] = r.y;
      pkTl[(u + 2) * 256 + n] = r.z; pkTl[(u + 3) * 256 + n] = r.w;
    } else {
      ((float4*)(P.pq + n * 512))[ug2] = r;
    }
  }
  __syncthreads();
}

// bias rows for layer lb: rare per-pair rows of own map-row + shared rows on 254/255
__device__ void b_bias(const Params& P, int b, int t, int lb,
                       float* smF, float* smG, float4* smV, int* smI) {
  if (t == 0) smI[256] = 0;
  __syncthreads();
  if (t < 256) {
    int mv = P.map[b * 256 + t];
    if (mv >= 0) { int i = atomicAdd(&smI[256], 1); smI[i] = mv; }
  }
  __syncthreads();
  const float* Wp = P.bpW + (size_t)lb * 65536;
  const float* Bp = P.bpB + lb * 512;
  const float* Wo = P.bowW + (size_t)lb * 65536;
  const float* Bo = P.bowB + lb * 128;
  int cnt = smI[256]; if (cnt > 256) cnt = 256;
  for (int i = 0; i < cnt; ++i)
    bias_row_pipe(P.specialBias + (size_t)smI[i] * 128, P.specialDiff + (size_t)smI[i] * 4,
                  Wp, Bp, Wo, Bo, smF, smG, smV, t);
  if (b == 254)
    bias_row_pipe(P.zeroBias, P.zeroDiff + (lb & 1) * 4, Wp, Bp, Wo, Bo, smF, smG, smV, t);
  if (b == 255)
    bias_row_pipe(P.genBias, P.genDiff + (lb & 1) * 4, Wp, Bp, Wo, Bo, smF, smG, smV, t);
}

// 256 blocks x 1024 threads, 4 grid syncs total
__global__ void __launch_bounds__(1024, 4) crakn(Params P) {
  cg::grid_group grid = cg::this_grid();
  const int b = blockIdx.x, t = threadIdx.x;
  const int lane = t & 63, wave = t >> 6;
  __shared__ float smF[1024];
  __shared__ float smG[1024];
  __shared__ float smH[160];
  __shared__ int smI[260];
  __shared__ float4 smV[1024];

  // ================= Phase A: node / pred0 / distances / RBF =================
  {
    const int n = b;
    if (t < 256) smF[t] = P.X[n * 256 + t];
    __syncthreads();
    {                                   // emb partials: d = t&63, 16 f-chunks
      const int d = t & 63, ch = t >> 6;
      const float* W = P.embW + (ch * 16) * 64 + d;
      const float* xr = smF + ch * 16;
      float acc = 0.f;
      #pragma unroll
      for (int f = 0; f < 16; ++f) acc = fmaf(xr[f], W[f * 64], acc);
      smG[t] = acc;
    }
    float pp = (t < 256) ? smF[t] * P.boutW[t] : 0.f;
    #pragma unroll
    for (int s = 32; s; s >>= 1) pp += __shfl_xor(pp, s);
    if (t < 256 && lane == 0) smH[128 + wave] = pp;
    __syncthreads();
    if (t < 64) {
      float nd = P.embB[t];
      #pragma unroll
      for (int j = 0; j < 16; ++j) nd += smG[t + 64 * j];
      P.q[n * 64 + t] = nd; P.k[n * 64 + t] = nd;
      smH[t] = nd; smH[64 + t] = nd;          // xs for b_proj(0)
    }
    if (t == 0) P.pred[n] = smH[128] + smH[129] + smH[130] + smH[131] + P.boutB[0];
    __syncthreads();
    if (t < 25) ((float4*)smG)[t] = ((const float4*)(P.E + n * 100))[t];
    if (t == 0) smI[256] = 0;
    __syncthreads();
    if (t < 256) {                      // distances, thread = m
      const int m = t;
      const float4* em = (const float4*)(P.E + m * 100);
      const float4* en = (const float4*)smG;
      float sq = 0.f;
      #pragma unroll 5
      for (int jj = 0; jj < 25; ++jj) {
        float4 a = en[jj], c = em[jj];
        float dx = a.x - c.x, dy = a.y - c.y, dz = a.z - c.z, dw = a.w - c.w;
        sq += dx * dx + dy * dy + dz * dz + dw * dw;
      }
      float dd = (sq > 0.f) ? sqrtf(sq) : 0.f;
      // exp(-127*(d-c)^2), c in [0,1]: fp32-underflows to exactly 0 for d>=1.905.
      // d==0 rows are all identical -> shared zero-row (exact dedup).
      int mv;
      if (dd == 0.f) mv = -2;
      else if (dd < 1.905f) {
        int i = atomicAdd(&smI[256], 1);
        smI[i] = m; smG[512 + i] = dd;
        mv = n * 256 + m;
      } else mv = -1;
      P.map[n * 256 + m] = mv;
    }
    __syncthreads();
    {                                   // rare per-pair RBF rows (none in practice)
      int cnt = smI[256]; if (cnt > 256) cnt = 256;
      for (int i = 0; i < cnt; ++i) if (t < 128) {
        float dd = smG[512 + i] - (float)t * (1.f / 127.f);
        P.specialBias[(size_t)(n * 256 + smI[i]) * 128 + t] = expf(-127.f * dd * dd);
      }
    }
    if (b == 254 && t < 128) {          // own-block init for B-phase bias rows
      float c = (float)t * (1.f / 127.f);
      P.zeroBias[t] = expf(-127.f * c * c);
    }
    if (b == 255 && t < 128) P.genBias[t] = 0.f;
    __syncthreads();
  }
  // B(0): projection + bias rows (no grid sync needed — all own-block deps)
  b_proj(P, b, t, 0, smH, smV);
  b_bias(P, b, t, 0, smF, smG, smV, smI);

  for (int l = 0; l < 4; ++l) {
    grid.sync();
    // ====== Phase C(l): attention + pred (block n = b) ======
    {
      const int n = b;
      const float4* pkT4 = (const float4*)(P.pkT + (size_t)(l & 1) * 131072);
      if (t < 128) ((float4*)smF)[t] = ((const float4*)(P.pq + n * 512))[t];
      __syncthreads();
      {
        const int h = t >> 8, jc = (t >> 6) & 3, mg = t & 63;
        const float* qv = smF + h * 128 + jc * 32;
        const float4* base = pkT4 + (size_t)(h * 128 + jc * 32) * 64 + mg;
        float4 acc = {0.f, 0.f, 0.f, 0.f};
        #pragma unroll 8
        for (int jj = 0; jj < 32; ++jj) {
          float a = qv[jj];
          float4 v = base[jj * 64];
          acc.x = fmaf(a, v.x, acc.x); acc.y = fmaf(a, v.y, acc.y);
          acc.z = fmaf(a, v.z, acc.z); acc.w = fmaf(a, v.w, acc.w);
        }
        smV[t] = acc;
      }
      __syncthreads();
      if (t < 256) {
        const int h2 = t >> 6, mg2 = t & 63;
        float4 dts = smV[h2 * 256 + mg2];
        #pragma unroll
        for (int kc = 1; kc < 4; ++kc) {
          float4 v = smV[h2 * 256 + kc * 64 + mg2];
          dts.x += v.x; dts.y += v.y; dts.z += v.z; dts.w += v.w;
        }
        const float* zD = P.zeroDiff + (l & 1) * 4;
        const float* gD = P.genDiff + (l & 1) * 4;
        const float predn = P.pred[n];
        float dArr[4] = {dts.x, dts.y, dts.z, dts.w};
        float lg[4], vl[4];
        #pragma unroll
        for (int i = 0; i < 4; ++i) {
          int m = mg2 * 4 + i;
          int sidx = P.map[n * 256 + m];
          float bd = (sidx == -2) ? zD[h2] : (sidx == -1) ? gD[h2]
                   : P.specialDiff[(size_t)sidx * 4 + h2];
          lg[i] = dArr[i] * 0.08838834764831845f + bd;   // 1/sqrt(128)
          vl[i] = (m == n) ? predn : P.nbr[m];
        }
        float wm = fmaxf(fmaxf(lg[0], lg[1]), fmaxf(lg[2], lg[3]));
        #pragma unroll
        for (int s = 32; s; s >>= 1) wm = fmaxf(wm, __shfl_xor(wm, s));
        float s1 = 0.f, s2 = 0.f;
        #pragma unroll
        for (int i = 0; i < 4; ++i) {
          float e = expf(lg[i] - wm);
          s1 += e; s2 += e * vl[i];
        }
        #pragma unroll
        for (int s = 32; s; s >>= 1) { s1 += __shfl_xor(s1, s); s2 += __shfl_xor(s2, s); }
        if (mg2 == 0) { smH[h2] = s1; smH[4 + h2] = s2; }
      }
      __syncthreads();
      if (t == 0) {
        float p = 0.25f * (smH[4] / smH[0] + smH[5] / smH[1]
                         + smH[6] / smH[2] + smH[7] / smH[3]);
        P.pred[n] = p;                       // only ever read by this block
        if (l == 3) P.out[n] = p;
      }
      __syncthreads();
    }
    if (l < 3) {
      // ====== B_update(l): residual/LN consuming layer-l pq/pk (own block) ======
      {
        const int n = b;
        const int group = t >> 9, u = t & 511;
        smF[t] = (group ? P.pk : P.pq)[n * 512 + u];
        __syncthreads();
        const float* W = (group ? P.koW : P.qoW) + (size_t)l * 32768;
        {
          const int d = u & 63, ch = u >> 6;
          const float* prow = smF + group * 512;
          float acc = 0.f;
          #pragma unroll 8
          for (int rr = 0; rr < 64; ++rr) {
            int r = ch * 64 + rr;
            acc = fmaf(prow[((r & 3) << 7) | (r >> 2)], W[r * 64 + d], acc);
          }
          smG[t] = acc;
        }
        __syncthreads();
        if (u < 64) {
          float* x = (group ? P.k : P.q) + n * 64;
          const float* B = (group ? P.koB : P.qoB) + l * 64;
          float acc = B[u];
          #pragma unroll
          for (int j = 0; j < 8; ++j) acc += smG[group * 512 + u + 64 * j];
          float xv = x[u] + mishf(acc);
          float mean = xv;
          #pragma unroll
          for (int s = 32; s; s >>= 1) mean += __shfl_xor(mean, s);
          mean *= (1.f / 64.f);
          float dv = xv - mean, var = dv * dv;
          #pragma unroll
          for (int s = 32; s; s >>= 1) var += __shfl_xor(var, s);
          var *= (1.f / 64.f);
          const float* G  = (group ? P.klnG : P.qlnG) + l * 64;
          const float* Bb = (group ? P.klnB : P.qlnB) + l * 64;
          float xn = dv * rsqrtf(var + 1e-5f) * G[u] + Bb[u];
          x[u] = xn; smH[group * 64 + u] = xn;
        }
        __syncthreads();
      }
      b_proj(P, b, t, l + 1, smH, smV);
      b_bias(P, b, t, l + 1, smF, smG, smV, smI);
    }
  }
}

// ---------------------------------------------------------------------------
extern "C" void kernel_launch(void* const* d_in, const int* in_sizes, int n_in,
                              void* d_out, int out_size, void* d_ws, size_t ws_size,
                              hipStream_t stream) {
  char* p = (char*)d_ws;
  auto carve = [&](size_t bytes) -> void* {
    void* r = (void*)p;
    p += (bytes + 255) & ~(size_t)255;
    return r;
  };

  Params P;
  P.X     = (const float*)d_in[0];
  P.E     = (const float*)d_in[1];
  P.nbr   = (const float*)d_in[2];
  P.embW  = (const float*)d_in[3];
  P.embB  = (const float*)d_in[4];
  P.boutW = (const float*)d_in[5];
  P.boutB = (const float*)d_in[6];
  P.qpW   = (const float*)d_in[7];
  P.qpB   = (const float*)d_in[8];
  P.kpW   = (const float*)d_in[9];
  P.kpB   = (const float*)d_in[10];
  P.qoW   = (const float*)d_in[11];
  P.qoB   = (const float*)d_in[12];
  P.koW   = (const float*)d_in[13];
  P.koB   = (const float*)d_in[14];
  P.bpW   = (const float*)d_in[15];
  P.bpB   = (const float*)d_in[16];
  P.bowW  = (const float*)d_in[17];
  P.bowB  = (const float*)d_in[18];
  P.qlnG  = (const float*)d_in[19];
  P.qlnB  = (const float*)d_in[20];
  P.klnG  = (const float*)d_in[21];
  P.klnB  = (const float*)d_in[22];
  P.out   = (float*)d_out;

  P.q           = (float*)carve(256 * 64 * 4);
  P.k           = (float*)carve(256 * 64 * 4);
  P.pq          = (float*)carve(256 * 512 * 4);
  P.pk          = (float*)carve(256 * 512 * 4);
  P.pkT         = (float*)carve((size_t)2 * 512 * 256 * 4);   // double-buffered
  P.pred        = (float*)carve(256 * 4);
  P.zeroBias    = (float*)carve(128 * 4);
  P.zeroDiff    = (float*)carve(2 * 4 * 4);                   // double-buffered
  P.genBias     = (float*)carve(128 * 4);
  P.genDiff     = (float*)carve(2 * 4 * 4);                   // double-buffered
  P.map         = (int*)carve((size_t)256 * 256 * 4);
  P.specialDiff = (float*)carve((size_t)65536 * 4 * 4);
  P.specialBias = (float*)carve((size_t)65536 * 128 * 4);

  void* args[] = { &P };
  hipLaunchCooperativeKernel((const void*)crakn, dim3(256), dim3(1024), args, 0, stream);
}

// Round 8
// 334.224 us; speedup vs baseline: 1.3227x; 1.3227x over previous
//
#include <hip/hip_runtime.h>
#include <hip/hip_cooperative_groups.h>

namespace cg = cooperative_groups;

struct Params {
  const float *X, *E, *nbr;
  const float *embW, *embB, *boutW, *boutB;
  const float *qpW, *qpB, *kpW, *kpB, *qoW, *qoB, *koW, *koB;
  const float *bpW, *bpB, *bowW, *bowB;
  const float *qlnG, *qlnB, *klnG, *klnB;
  float *out;
  float *pkT;          // [2][512][256] double-buffered (cross-block)
  float *zDiff;        // [2][4] double-buffered (cross-block)
  float *gDiff;        // [2][4]
  float *specialBias;  // rare-pair rows (own-block only)
};

__device__ __forceinline__ float mishf(float x) {
  float sp = (x > 20.f) ? x : log1pf(expf(x));
  return x * tanhf(sp);
}

// One bias row through one layer (1024 threads; row/drow may be LDS or global):
//   b = row@Wp + Bp ; drow_h = ||b_h|| ; row' = mish(b@Wo + Bo)
__device__ void bias_row_pipe(float* row, float* drow,
                              const float* __restrict__ Wp, const float* __restrict__ Bp,
                              const float* __restrict__ Wo, const float* __restrict__ Bo,
                              float* smW, float* smB, int t) {
  const int lane = t & 63, wave = t >> 6;
  if (t < 128) smB[t] = row[t];
  __syncthreads();
  {                                     // GEMM1 [128x512]: split-K halves of 64
    const int o = t & 511, kh = t >> 9;
    const float* Wc = Wp + (kh * 64) * 512 + o;
    const float* rc = smB + kh * 64;
    float a = (kh == 0) ? Bp[o] : 0.f;
    #pragma unroll 8
    for (int c = 0; c < 64; ++c) a = fmaf(rc[c], Wc[c * 512], a);
    smW[t] = a;
  }
  __syncthreads();
  if (t < 512) smB[128 + t] = smW[t] + smW[512 + t];   // b[512] at smB[128..639]
  __syncthreads();
  if (wave < 4) {                       // per-head norm, wave = head
    float e1 = smB[128 + wave * 128 + lane], e2 = smB[128 + wave * 128 + 64 + lane];
    float s = e1 * e1 + e2 * e2;
    #pragma unroll
    for (int sh = 32; sh; sh >>= 1) s += __shfl_xor(s, sh);
    if (lane == 0) drow[wave] = sqrtf(s);
  }
  {                                     // GEMM2 [512x128]: 8 K-chunks of 64
    const int c = t & 127, ch = t >> 7;
    const float* Woc = Wo + (ch * 64) * 128 + c;
    const float* bc = smB + 128 + ch * 64;
    float a = 0.f;
    #pragma unroll 8
    for (int o2 = 0; o2 < 64; ++o2) a = fmaf(bc[o2], Woc[o2 * 128], a);
    smW[t] = a;
  }
  __syncthreads();
  if (t < 128) {
    float a = Bo[t];
    #pragma unroll
    for (int j = 0; j < 8; ++j) a += smW[t + 128 * j];
    row[t] = mishf(a);
  }
  __syncthreads();
}

// 256 blocks x 1024 threads, 1 block/CU; ALL per-n state persists in LDS.
__global__ void __launch_bounds__(1024, 4) crakn(Params P) {
  cg::grid_group grid = cg::this_grid();
  const int b = blockIdx.x, t = threadIdx.x;
  const int lane = t & 63, wave = t >> 6;
  const int n = b;

  // ---- persistent (survive grid.sync; LDS is never invalidated) ----
  __shared__ float smP[512];     // pq row
  __shared__ float smKr[512];    // pk row
  __shared__ float smQ[64], smKq[64];   // q, k rows
  __shared__ float smNbr[256];
  __shared__ int   smMap[256];   // -2 self(d==0), -1 generic, >=0 rare-pair idx
  __shared__ float smPD[2048];   // rare diffs [pair][parity][4]
  __shared__ float smZrow[128];  // zero/gen bias row (blocks 254/255)
  __shared__ float smPred[1];
  __shared__ int   smI[257];     // rare list + count
  __shared__ float smD[256];     // rare dists
  // ---- scratch ----
  __shared__ float smW[1024];
  __shared__ float smB[640];
  __shared__ float smH[64];

  // ================= Phase A =================
  {
    if (t < 256) smB[t] = P.X[n * 256 + t];
    if (t == 0) smI[256] = 0;
    __syncthreads();
    {                                   // emb partials: d = t&63, 16 K-chunks of 16
      const int d = t & 63, ch = t >> 6;
      const float* W = P.embW + (ch * 16) * 64 + d;
      const float* xr = smB + ch * 16;
      float acc = 0.f;
      #pragma unroll
      for (int f = 0; f < 16; ++f) acc = fmaf(xr[f], W[f * 64], acc);
      smW[t] = acc;
    }
    float pp = (t < 256) ? smB[t] * P.boutW[t] : 0.f;
    #pragma unroll
    for (int s = 32; s; s >>= 1) pp += __shfl_xor(pp, s);
    if (t < 256 && lane == 0) smH[wave] = pp;
    if (t < 256) smNbr[t] = P.nbr[t];
    __syncthreads();
    if (t < 64) {
      float nd = P.embB[t];
      #pragma unroll
      for (int j = 0; j < 16; ++j) nd += smW[t + 64 * j];
      smQ[t] = nd; smKq[t] = nd;
    }
    if (t == 0) smPred[0] = smH[0] + smH[1] + smH[2] + smH[3] + P.boutB[0];
    __syncthreads();
    if (t < 25) ((float4*)(smB + 384))[t] = ((const float4*)(P.E + n * 100))[t];
    __syncthreads();
    if (t < 256) {                      // distances, thread = m
      const int m = t;
      const float4* em = (const float4*)(P.E + m * 100);
      const float4* en = (const float4*)(smB + 384);
      float sq = 0.f;
      #pragma unroll 5
      for (int jj = 0; jj < 25; ++jj) {
        float4 a = en[jj], c = em[jj];
        float dx = a.x - c.x, dy = a.y - c.y, dz = a.z - c.z, dw = a.w - c.w;
        sq += dx * dx + dy * dy + dz * dz + dw * dw;
      }
      float dd = (sq > 0.f) ? sqrtf(sq) : 0.f;
      // exp(-127*(d-c)^2), c in [0,1]: fp32-underflows to exactly 0 for d>=1.905.
      // d==0 rows are identical across pairs -> one shared zero-row (exact dedup).
      int mv;
      if (dd == 0.f) mv = -2;
      else if (dd < 1.905f) {
        int i = atomicAdd(&smI[256], 1);
        smI[i] = m; smD[i] = dd;
        mv = i;     // resolved to pair idx after scan (same value)
      } else mv = -1;
      smMap[m] = mv;
    }
    if ((b == 254 || b == 255) && t < 128) {
      float c = (float)t * (1.f / 127.f);
      smZrow[t] = (b == 254) ? expf(-127.f * c * c) : 0.f;
    }
    __syncthreads();
    // fix rare map values to list order (atomic order == smI order already; but
    // smMap stored provisional idx which IS the list idx — consistent) and
    // write rare RBF rows to global scratch
    {
      int cnt = smI[256]; if (cnt > 256) cnt = 256;
      for (int i = 0; i < cnt; ++i) if (t < 128) {
        float dd = smD[i] - (float)t * (1.f / 127.f);
        P.specialBias[(size_t)(n * 256 + i) * 128 + t] = expf(-127.f * dd * dd);
      }
    }
    __syncthreads();
    // proj(0): g = t>>9 (0=q,1=k), u = t&511, coalesced scalar weight reads
    {
      const int g = t >> 9, u = t & 511;
      const float* Wp = (g ? P.kpW : P.qpW);
      const float* Bp = (g ? P.kpB : P.qpB);
      const float* xs = g ? smKq : smQ;
      float a = Bp[u];
      #pragma unroll 8
      for (int d = 0; d < 64; ++d) a = fmaf(xs[d], Wp[d * 512 + u], a);
      if (g) { smKr[u] = a; P.pkT[u * 256 + n] = a; }
      else   { smP[u] = a; }
    }
    // pipes layer 0 (block-uniform branches; __syncthreads inside is safe)
    {
      int cnt = smI[256]; if (cnt > 256) cnt = 256;
      for (int i = 0; i < cnt; ++i)
        bias_row_pipe(P.specialBias + (size_t)(n * 256 + i) * 128, smPD + i * 8,
                      P.bpW, P.bpB, P.bowW, P.bowB, smW, smB, t);
      if (b == 254) bias_row_pipe(smZrow, P.zDiff, P.bpW, P.bpB, P.bowW, P.bowB, smW, smB, t);
      if (b == 255) bias_row_pipe(smZrow, P.gDiff, P.bpW, P.bpB, P.bowW, P.bowB, smW, smB, t);
    }
  }

  for (int l = 0; l < 4; ++l) {
    grid.sync();
    const int par = l & 1;
    // ====== C(l): attention + pred; everything own-block except pkT/diffs ======
    {
      const int h = t >> 8, m = t & 255;
      const int cls = smMap[m];
      const float bd = (cls == -2) ? P.zDiff[par * 4 + h]
                     : (cls == -1) ? P.gDiff[par * 4 + h]
                     : smPD[cls * 8 + par * 4 + h];
      const float val = (m == n) ? smPred[0] : smNbr[m];
      const float* pt = P.pkT + (size_t)par * 131072 + (size_t)(h * 128) * 256 + m;
      const float* qv = smP + h * 128;
      float dot = 0.f;
      #pragma unroll 8
      for (int j = 0; j < 128; ++j) dot = fmaf(qv[j], pt[j * 256], dot);
      float lg = dot * 0.08838834764831845f + bd;   // 1/sqrt(128)
      float wm = lg;
      #pragma unroll
      for (int s = 32; s; s >>= 1) wm = fmaxf(wm, __shfl_xor(wm, s));
      if (lane == 0) smH[wave] = wm;
      __syncthreads();
      float mx = fmaxf(fmaxf(smH[h * 4], smH[h * 4 + 1]),
                       fmaxf(smH[h * 4 + 2], smH[h * 4 + 3]));
      float e = expf(lg - mx);
      float s1 = e, s2 = e * val;
      #pragma unroll
      for (int s = 32; s; s >>= 1) { s1 += __shfl_xor(s1, s); s2 += __shfl_xor(s2, s); }
      if (lane == 0) { smH[16 + wave] = s1; smH[32 + wave] = s2; }
      __syncthreads();
      if (t == 0) {
        float p = 0.f;
        #pragma unroll
        for (int hh = 0; hh < 4; ++hh) {
          float den = smH[16 + hh * 4] + smH[17 + hh * 4] + smH[18 + hh * 4] + smH[19 + hh * 4];
          float ws  = smH[32 + hh * 4] + smH[33 + hh * 4] + smH[34 + hh * 4] + smH[35 + hh * 4];
          p += 0.25f * (ws / den);
        }
        smPred[0] = p;
        if (l == 3) P.out[n] = p;
      }
      __syncthreads();
    }
    if (l == 3) break;
    // ====== Bupd(l): q/k residual + mish + LN (all LDS state) ======
    {
      const int g = t >> 9, u = t & 511;
      const float* prow = g ? smKr : smP;
      const float* W = (g ? P.koW : P.qoW) + (size_t)l * 32768;
      {
        const int d = u & 63, ch = u >> 6;
        float acc = 0.f;
        #pragma unroll 8
        for (int rr = 0; rr < 64; ++rr) {
          int r = ch * 64 + rr;
          acc = fmaf(prow[((r & 3) << 7) | (r >> 2)], W[r * 64 + d], acc);
        }
        smW[t] = acc;
      }
      __syncthreads();
      if (u < 64) {
        float* x = g ? smKq : smQ;
        const float* B = (g ? P.koB : P.qoB) + l * 64;
        float acc = B[u];
        #pragma unroll
        for (int j = 0; j < 8; ++j) acc += smW[g * 512 + u + 64 * j];
        float xv = x[u] + mishf(acc);
        float mean = xv;
        #pragma unroll
        for (int s = 32; s; s >>= 1) mean += __shfl_xor(mean, s);
        mean *= (1.f / 64.f);
        float dv = xv - mean, var = dv * dv;
        #pragma unroll
        for (int s = 32; s; s >>= 1) var += __shfl_xor(var, s);
        var *= (1.f / 64.f);
        const float* G  = (g ? P.klnG : P.qlnG) + l * 64;
        const float* Bb = (g ? P.klnB : P.qlnB) + l * 64;
        x[u] = dv * rsqrtf(var + 1e-5f) * G[u] + Bb[u];
      }
      __syncthreads();
    }
    // ====== proj(l+1) ======
    {
      const int g = t >> 9, u = t & 511;
      const float* Wp = (g ? P.kpW : P.qpW) + (size_t)(l + 1) * 32768;
      const float* Bp = (g ? P.kpB : P.qpB) + (l + 1) * 512;
      const float* xs = g ? smKq : smQ;
      float a = Bp[u];
      #pragma unroll 8
      for (int d = 0; d < 64; ++d) a = fmaf(xs[d], Wp[d * 512 + u], a);
      if (g) { smKr[u] = a; P.pkT[(size_t)((l + 1) & 1) * 131072 + u * 256 + n] = a; }
      else   { smP[u] = a; }
    }
    // ====== pipes for layer l+1 (lazy; overlaps other blocks' region work) ======
    {
      const int np = (l + 1) & 1;
      const float* Wp = P.bpW + (size_t)(l + 1) * 65536;
      const float* Bp = P.bpB + (l + 1) * 512;
      const float* Wo = P.bowW + (size_t)(l + 1) * 65536;
      const float* Bo = P.bowB + (l + 1) * 128;
      int cnt = smI[256]; if (cnt > 256) cnt = 256;
      for (int i = 0; i < cnt; ++i)
        bias_row_pipe(P.specialBias + (size_t)(n * 256 + i) * 128, smPD + i * 8 + np * 4,
                      Wp, Bp, Wo, Bo, smW, smB, t);
      if (b == 254) bias_row_pipe(smZrow, P.zDiff + np * 4, Wp, Bp, Wo, Bo, smW, smB, t);
      if (b == 255) bias_row_pipe(smZrow, P.gDiff + np * 4, Wp, Bp, Wo, Bo, smW, smB, t);
    }
  }
}

// ---------------------------------------------------------------------------
extern "C" void kernel_launch(void* const* d_in, const int* in_sizes, int n_in,
                              void* d_out, int out_size, void* d_ws, size_t ws_size,
                              hipStream_t stream) {
  char* p = (char*)d_ws;
  auto carve = [&](size_t bytes) -> void* {
    void* r = (void*)p;
    p += (bytes + 255) & ~(size_t)255;
    return r;
  };

  Params P;
  P.X     = (const float*)d_in[0];
  P.E     = (const float*)d_in[1];
  P.nbr   = (const float*)d_in[2];
  P.embW  = (const float*)d_in[3];
  P.embB  = (const float*)d_in[4];
  P.boutW = (const float*)d_in[5];
  P.boutB = (const float*)d_in[6];
  P.qpW   = (const float*)d_in[7];
  P.qpB   = (const float*)d_in[8];
  P.kpW   = (const float*)d_in[9];
  P.kpB   = (const float*)d_in[10];
  P.qoW   = (const float*)d_in[11];
  P.qoB   = (const float*)d_in[12];
  P.koW   = (const float*)d_in[13];
  P.koB   = (const float*)d_in[14];
  P.bpW   = (const float*)d_in[15];
  P.bpB   = (const float*)d_in[16];
  P.bowW  = (const float*)d_in[17];
  P.bowB  = (const float*)d_in[18];
  P.qlnG  = (const float*)d_in[19];
  P.qlnB  = (const float*)d_in[20];
  P.klnG  = (const float*)d_in[21];
  P.klnB  = (const float*)d_in[22];
  P.out   = (float*)d_out;

  P.pkT         = (float*)carve((size_t)2 * 512 * 256 * 4);
  P.zDiff       = (float*)carve(2 * 4 * 4);
  P.gDiff       = (float*)carve(2 * 4 * 4);
  P.specialBias = (float*)carve((size_t)65536 * 128 * 4);

  void* args[] = { &P };
  hipLaunchCooperativeKernel((const void*)crakn, dim3(256), dim3(1024), args, 0, stream);
}